// Round 2
// baseline (1992.966 us; speedup 1.0000x reference)
//
#include <hip/hip_runtime.h>

#define K_ORDER 10
#define NFEAT 512
#define NHID 256
#define NOUT 64
#define PI_F 3.14159265358979323846f

typedef __bf16 bf16x8 __attribute__((ext_vector_type(8)));
typedef unsigned short ushort8 __attribute__((ext_vector_type(8)));
typedef float f32x4 __attribute__((ext_vector_type(4)));

// ---------------- input dtype detection ----------------
// temp = 1.0 + 0.1*N(0,1): as bf16 all 11 shorts in [0x3E00,0x4080);
// as f32 only ~5 of the first 11 shorts (the high halves) are.
__global__ void detect_kernel(const unsigned short* __restrict__ temp, int* __restrict__ flag) {
    if (threadIdx.x == 0 && blockIdx.x == 0) {
        int cnt = 0;
        for (int i = 0; i < K_ORDER + 1; ++i) {
            unsigned short s = temp[i];
            if (s >= 0x3E00 && s < 0x4080) cnt++;
        }
        flag[0] = (cnt >= 9) ? 1 : 0;
    }
}

// ---------------- graph preprocessing ----------------

__global__ void count_deg_kernel(const int* __restrict__ row, int* __restrict__ deg, int e) {
    int i = blockIdx.x * blockDim.x + threadIdx.x;
    if (i < e) atomicAdd(&deg[row[i]], 1);
}

__global__ void dinv_kernel(const int* __restrict__ deg, float* __restrict__ dinv, int n) {
    int i = blockIdx.x * blockDim.x + threadIdx.x;
    if (i < n) {
        int d = deg[i];
        dinv[i] = (d > 0) ? rsqrtf((float)d) : 0.0f;
    }
}

// single-block exclusive prefix sum over deg[0..n-1] -> rowptr[0..n], cursor copy
__global__ __launch_bounds__(1024) void scan_kernel(const int* __restrict__ deg,
                                                    int* __restrict__ rowptr,
                                                    int* __restrict__ cursor, int n) {
    __shared__ int wtot[16];
    __shared__ int woff[16];
    __shared__ int s_chunk;
    __shared__ int s_carry;
    int tid = threadIdx.x;
    int lane = tid & 63, wid = tid >> 6;
    if (tid == 0) s_carry = 0;
    __syncthreads();
    for (int base = 0; base < n; base += 1024) {
        int i = base + tid;
        int v = (i < n) ? deg[i] : 0;
        int x = v;
        #pragma unroll
        for (int off = 1; off < 64; off <<= 1) {
            int y = __shfl_up(x, off, 64);
            if (lane >= off) x += y;
        }
        if (lane == 63) wtot[wid] = x;
        __syncthreads();
        if (wid == 0) {
            int t = (lane < 16) ? wtot[lane] : 0;
            int s = t;
            #pragma unroll
            for (int off = 1; off < 16; off <<= 1) {
                int y = __shfl_up(s, off, 64);
                if (lane >= off) s += y;
            }
            if (lane < 16) woff[lane] = s - t;
            if (lane == 15) s_chunk = s;
        }
        __syncthreads();
        int carry = s_carry;
        int excl = carry + woff[wid] + (x - v);
        if (i < n) { rowptr[i] = excl; cursor[i] = excl; }
        __syncthreads();
        if (tid == 0) s_carry = carry + s_chunk;
    }
    __syncthreads();
    if (tid == 0) rowptr[n] = s_carry;
}

__global__ void scatter_kernel(const int* __restrict__ row, const int* __restrict__ col,
                               const float* __restrict__ dinv, int* __restrict__ cursor,
                               int* __restrict__ cols_s, float* __restrict__ w_s, int e) {
    int i = blockIdx.x * blockDim.x + threadIdx.x;
    if (i < e) {
        int r = row[i], c = col[i];
        int p = atomicAdd(&cursor[r], 1);
        cols_s[p] = c;
        w_s[p] = -dinv[r] * dinv[c];
    }
}

// ---------------- Chebyshev coefficients ----------------

__global__ void coef_kernel(const void* __restrict__ temp, const int* __restrict__ flag,
                            float* __restrict__ coe) {
    int i = threadIdx.x;
    bool isbf = flag[0] != 0;
    if (i <= K_ORDER) {
        float s = 0.0f;
        #pragma unroll
        for (int j = 0; j <= K_ORDER; ++j) {
            float t = isbf ? (float)((const __bf16*)temp)[j] : ((const float*)temp)[j];
            t = fmaxf(t, 0.0f);
            float theta = ((float)(K_ORDER - j) + 0.5f) * PI_F / (float)(K_ORDER + 1);
            s += cosf((float)i * theta) * t;
        }
        coe[i] = (2.0f / (float)(K_ORDER + 1)) * s;
    }
}

// ---------------- MFMA GEMM:  C[M,*] = A[M,K] @ B[ncols,K]^T (+bias, opt relu), bf16 out ----
// A_FLAGGED: A dtype per flag (external input); else A is internal bf16.
// B and bias are always external (dtype per flag).

template<int BN, bool RELU, bool A_FLAGGED>
__global__ __launch_bounds__(256) void gemm_kernel(const void* __restrict__ A,
                                                   const void* __restrict__ B,
                                                   const void* __restrict__ bias,
                                                   const int* __restrict__ flag,
                                                   unsigned short* __restrict__ C,
                                                   int M, int Kdim, int ldc) {
    constexpr int BM = 128, BK = 32;
    constexpr int FN = BN / 32;
    constexpr int LDT = BK + 8;      // 80B row stride: 16B-aligned, only 2-way bank alias (free)
    __shared__ unsigned short lds_a[BM * LDT] __attribute__((aligned(16)));
    __shared__ unsigned short lds_b[BN * LDT] __attribute__((aligned(16)));

    const bool isbf = flag[0] != 0;
    int tid = threadIdx.x;
    int lane = tid & 63, wid = tid >> 6;
    int row0 = blockIdx.x * BM;
    int col0 = blockIdx.y * BN;
    int wrow = (wid >> 1) * (BM / 2);
    int wcol = (wid & 1) * (BN / 2);

    f32x4 acc[4][FN] = {};

    for (int k0 = 0; k0 < Kdim; k0 += BK) {
        // stage A tile
        #pragma unroll
        for (int it = 0; it < (BM * BK / 8) / 256; ++it) {
            int idx = it * 256 + tid;
            int r = idx >> 2;
            int kc = (idx & 3) * 8;
            int gr = row0 + r; if (gr >= M) gr = M - 1;
            size_t base = (size_t)gr * Kdim + k0 + kc;
            if (!A_FLAGGED || isbf) {
                *(ushort8*)&lds_a[r * LDT + kc] = *(const ushort8*)((const unsigned short*)A + base);
            } else {
                const float* Af = (const float*)A;
                f32x4 lo = *(const f32x4*)(Af + base);
                f32x4 hi = *(const f32x4*)(Af + base + 4);
                bf16x8 v;
                #pragma unroll
                for (int j = 0; j < 4; ++j) { v[j] = (__bf16)lo[j]; v[j + 4] = (__bf16)hi[j]; }
                *(bf16x8*)&lds_a[r * LDT + kc] = v;
            }
        }
        // stage B tile
        #pragma unroll
        for (int it = 0; it < (BN * BK / 8) / 256; ++it) {
            int idx = it * 256 + tid;
            int r = idx >> 2;
            int kc = (idx & 3) * 8;
            size_t base = (size_t)(col0 + r) * Kdim + k0 + kc;
            if (isbf) {
                *(ushort8*)&lds_b[r * LDT + kc] = *(const ushort8*)((const unsigned short*)B + base);
            } else {
                const float* Bf = (const float*)B;
                f32x4 lo = *(const f32x4*)(Bf + base);
                f32x4 hi = *(const f32x4*)(Bf + base + 4);
                bf16x8 v;
                #pragma unroll
                for (int j = 0; j < 4; ++j) { v[j] = (__bf16)lo[j]; v[j + 4] = (__bf16)hi[j]; }
                *(bf16x8*)&lds_b[r * LDT + kc] = v;
            }
        }
        __syncthreads();

        int kq = (lane >> 4) * 8;
        bf16x8 af[4];
        bf16x8 bfr[FN];
        #pragma unroll
        for (int mi = 0; mi < 4; ++mi)
            af[mi] = *(bf16x8*)&lds_a[(wrow + mi * 16 + (lane & 15)) * LDT + kq];
        #pragma unroll
        for (int ni = 0; ni < FN; ++ni)
            bfr[ni] = *(bf16x8*)&lds_b[(wcol + ni * 16 + (lane & 15)) * LDT + kq];
        #pragma unroll
        for (int mi = 0; mi < 4; ++mi)
            #pragma unroll
            for (int ni = 0; ni < FN; ++ni)
                acc[mi][ni] = __builtin_amdgcn_mfma_f32_16x16x32_bf16(af[mi], bfr[ni],
                                                                      acc[mi][ni], 0, 0, 0);
        __syncthreads();
    }

    // epilogue: C/D layout col=lane&15, row=(lane>>4)*4+reg
    #pragma unroll
    for (int mi = 0; mi < 4; ++mi) {
        #pragma unroll
        for (int ni = 0; ni < FN; ++ni) {
            #pragma unroll
            for (int rg = 0; rg < 4; ++rg) {
                int grow = row0 + wrow + mi * 16 + (lane >> 4) * 4 + rg;
                int gcol = col0 + wcol + ni * 16 + (lane & 15);
                if (grow < M) {
                    float bb = isbf ? (float)((const __bf16*)bias)[gcol]
                                    : ((const float*)bias)[gcol];
                    float vv = acc[mi][ni][rg] + bb;
                    if (RELU) vv = fmaxf(vv, 0.0f);
                    __bf16 h = (__bf16)vv;
                    C[(size_t)grow * ldc + gcol] = *(unsigned short*)&h;
                }
            }
        }
    }
}

// ---------------- Chebyshev propagation: one wave per row, lane = feature ----------
// mode 0: tdst (write-only) = P*vsrc; outacc = coe0/2*vsrc[own] + coe1*P*vsrc
// mode 1: t2 = 2*P*vsrc - tdst[own]; tdst[own] = t2 (in place); outacc += coe[ci]*t2

__global__ __launch_bounds__(256) void prop_kernel(const unsigned short* __restrict__ vsrc,
                                                   unsigned short* __restrict__ tdst,
                                                   float* __restrict__ outacc,
                                                   const int* __restrict__ rowptr,
                                                   const int* __restrict__ cols,
                                                   const float* __restrict__ wgt,
                                                   const float* __restrict__ coe,
                                                   int mode, int ci, int n) {
    int lane = threadIdx.x & 63;
    int r = blockIdx.x * (blockDim.x >> 6) + (threadIdx.x >> 6);
    if (r >= n) return;
    int e0 = rowptr[r], e1 = rowptr[r + 1];
    const __bf16* vb = (const __bf16*)vsrc;
    float acc = 0.0f;
    int e = e0;
    for (; e + 3 < e1; e += 4) {
        int c0 = cols[e + 0], c1 = cols[e + 1], c2 = cols[e + 2], c3 = cols[e + 3];
        float w0 = wgt[e + 0], w1 = wgt[e + 1], w2 = wgt[e + 2], w3 = wgt[e + 3];
        float v0 = (float)vb[c0 * NOUT + lane];
        float v1 = (float)vb[c1 * NOUT + lane];
        float v2 = (float)vb[c2 * NOUT + lane];
        float v3 = (float)vb[c3 * NOUT + lane];
        acc = fmaf(w0, v0, acc);
        acc = fmaf(w1, v1, acc);
        acc = fmaf(w2, v2, acc);
        acc = fmaf(w3, v3, acc);
    }
    for (; e < e1; ++e) acc = fmaf(wgt[e], (float)vb[cols[e] * NOUT + lane], acc);

    int idx = r * NOUT + lane;
    if (mode == 0) {
        __bf16 h = (__bf16)acc;
        tdst[idx] = *(unsigned short*)&h;
        float tx0 = (float)vb[idx];
        outacc[idx] = coe[0] * 0.5f * tx0 + coe[1] * acc;
    } else {
        float t0own = (float)((const __bf16*)tdst)[idx];
        float t2 = 2.0f * acc - t0own;
        __bf16 h = (__bf16)t2;
        tdst[idx] = *(unsigned short*)&h;
        outacc[idx] += coe[ci] * t2;
    }
}

__global__ void convert_kernel(const float* __restrict__ in, const int* __restrict__ flag,
                               void* __restrict__ out, int n) {
    int i = blockIdx.x * blockDim.x + threadIdx.x;
    bool isbf = flag[0] != 0;
    if (i < n) {
        float v = in[i];
        if (isbf) {
            __bf16 h = (__bf16)v;
            ((unsigned short*)out)[i] = *(unsigned short*)&h;
        } else {
            ((float*)out)[i] = v;
        }
    }
}

// ---------------- launch ----------------

extern "C" void kernel_launch(void* const* d_in, const int* in_sizes, int n_in,
                              void* d_out, int out_size, void* d_ws, size_t ws_size,
                              hipStream_t stream) {
    const void* feature = d_in[0];
    const void* W1      = d_in[1];
    const void* b1      = d_in[2];
    const void* W2      = d_in[3];
    const void* b2      = d_in[4];
    const void* temp    = d_in[5];
    const int* edge_index = (const int*)d_in[6];

    const int N = in_sizes[0] / NFEAT;   // 100000
    const int E = in_sizes[6] / 2;       // 3200000
    const int* row = edge_index;
    const int* col = edge_index + E;

    char* base = (char*)d_ws;
    size_t off = 0;
    auto alloc = [&](size_t bytes) -> char* {
        char* p = base + off;
        off = (off + bytes + 255) & ~(size_t)255;
        return p;
    };
    int*   flag   = (int*)  alloc(4);
    float* coe    = (float*)alloc(64);
    float* dinv   = (float*)alloc((size_t)N * 4);
    int*   deg    = (int*)  alloc((size_t)N * 4);
    int*   rowptr = (int*)  alloc((size_t)(N + 1) * 4);
    int*   cursor = (int*)  alloc((size_t)(N + 1) * 4);
    // overlay region R: xhid (N*NHID*2 = 51.2MB) lives gemm1->gemm2;
    // afterwards colss (E*4) | wss (E*4) | outacc (N*NOUT*4) live there. Exact fit.
    char*  R      = alloc((size_t)N * NHID * 2);
    unsigned short* xhid = (unsigned short*)R;
    int*   colss  = (int*)R;
    float* wss    = (float*)(R + (size_t)E * 4);
    float* outacc = (float*)(R + (size_t)E * 8);
    unsigned short* t_a = (unsigned short*)alloc((size_t)N * NOUT * 2);
    unsigned short* t_b = (unsigned short*)alloc((size_t)N * NOUT * 2);

    // dtype flag + coefficients
    detect_kernel<<<1, 64, 0, stream>>>((const unsigned short*)temp, flag);
    coef_kernel<<<1, 64, 0, stream>>>(temp, flag, coe);

    // dense MLP (writes xhid, then t_a = Tx0 bf16)
    gemm_kernel<128, true, true><<<dim3((N + 127) / 128, NHID / 128), 256, 0, stream>>>(
        feature, W1, b1, flag, xhid, N, NFEAT, NHID);
    gemm_kernel<64, false, false><<<dim3((N + 127) / 128, 1), 256, 0, stream>>>(
        xhid, W2, b2, flag, t_a, N, NHID, NOUT);

    // graph preprocessing (xhid dead now; colss/wss/outacc overlay it)
    hipMemsetAsync(deg, 0, (size_t)N * 4, stream);
    count_deg_kernel<<<(E + 255) / 256, 256, 0, stream>>>(row, deg, E);
    dinv_kernel<<<(N + 255) / 256, 256, 0, stream>>>(deg, dinv, N);
    scan_kernel<<<1, 1024, 0, stream>>>(deg, rowptr, cursor, N);
    scatter_kernel<<<(E + 255) / 256, 256, 0, stream>>>(row, col, dinv, cursor, colss, wss, E);

    // Chebyshev propagation with 2 ping-pong bf16 buffers
    int pb = (N + 3) / 4;
    prop_kernel<<<pb, 256, 0, stream>>>(t_a, t_b, outacc, rowptr, colss, wss, coe, 0, 0, N);
    unsigned short* src = t_b;
    unsigned short* dst = t_a;
    for (int i = 2; i <= K_ORDER; ++i) {
        prop_kernel<<<pb, 256, 0, stream>>>(src, dst, outacc, rowptr, colss, wss, coe, 1, i, N);
        unsigned short* tmp = src; src = dst; dst = tmp;
    }

    convert_kernel<<<(N * NOUT + 255) / 256, 256, 0, stream>>>(outacc, flag, d_out, N * NOUT);
}

// Round 3
// 1598.102 us; speedup vs baseline: 1.2471x; 1.2471x over previous
//
#include <hip/hip_runtime.h>

#define K_ORDER 10
#define NFEAT 512
#define NHID 256
#define NOUT 64
#define PI_F 3.14159265358979323846f
#define SCAN_CHUNK 2048

typedef __bf16 bf16x8 __attribute__((ext_vector_type(8)));
typedef unsigned short ushort8 __attribute__((ext_vector_type(8)));
typedef float f32x4 __attribute__((ext_vector_type(4)));

__device__ __forceinline__ float bf2f(unsigned short u) {
    union { unsigned int i; float f; } x;
    x.i = ((unsigned int)u) << 16;
    return x.f;
}

// ---------------- input dtype detection ----------------
__global__ void detect_kernel(const unsigned short* __restrict__ temp, int* __restrict__ flag) {
    if (threadIdx.x == 0 && blockIdx.x == 0) {
        int cnt = 0;
        for (int i = 0; i < K_ORDER + 1; ++i) {
            unsigned short s = temp[i];
            if (s >= 0x3E00 && s < 0x4080) cnt++;
        }
        flag[0] = (cnt >= 9) ? 1 : 0;
    }
}

// ---------------- graph preprocessing ----------------

__global__ void count_deg_kernel(const int* __restrict__ row, int* __restrict__ deg, int e) {
    int i = blockIdx.x * blockDim.x + threadIdx.x;
    if (i < e) atomicAdd(&deg[row[i]], 1);
}

__global__ void dinv_kernel(const int* __restrict__ deg, float* __restrict__ dinv, int n) {
    int i = blockIdx.x * blockDim.x + threadIdx.x;
    if (i < n) {
        int d = deg[i];
        dinv[i] = (d > 0) ? rsqrtf((float)d) : 0.0f;
    }
}

// ---- multi-block exclusive scan of deg -> rowptr/cursor (3 kernels) ----

__global__ __launch_bounds__(256) void partial_sum_kernel(const int* __restrict__ deg,
                                                          int* __restrict__ bsum, int n) {
    __shared__ int ws[4];
    int b = blockIdx.x, t = threadIdx.x;
    int base = b * SCAN_CHUNK + t * 8;
    int s = 0;
    #pragma unroll
    for (int j = 0; j < 8; ++j) { int i = base + j; if (i < n) s += deg[i]; }
    #pragma unroll
    for (int m = 1; m < 64; m <<= 1) s += __shfl_xor(s, m, 64);
    if ((t & 63) == 0) ws[t >> 6] = s;
    __syncthreads();
    if (t == 0) bsum[b] = ws[0] + ws[1] + ws[2] + ws[3];
}

// 1 block, 64 threads; nb <= 64
__global__ void scan_small_kernel(const int* __restrict__ bsum, int* __restrict__ boff,
                                  int* __restrict__ rowptr, int nb, int n) {
    int t = threadIdx.x;
    int v = (t < nb) ? bsum[t] : 0;
    int x = v;
    #pragma unroll
    for (int m = 1; m < 64; m <<= 1) { int y = __shfl_up(x, m, 64); if (t >= m) x += y; }
    if (t < nb) boff[t] = x - v;
    if (t == 63) rowptr[n] = x;
}

__global__ __launch_bounds__(256) void scan_apply_kernel(const int* __restrict__ deg,
                                                         const int* __restrict__ boff,
                                                         int* __restrict__ rowptr,
                                                         int* __restrict__ cursor, int n) {
    __shared__ int wtot[4];
    __shared__ int woff_s[4];
    int b = blockIdx.x, t = threadIdx.x;
    int lane = t & 63, wid = t >> 6;
    int base = b * SCAN_CHUNK + t * 8;
    int v[8], s[8];
    int run = 0;
    #pragma unroll
    for (int j = 0; j < 8; ++j) {
        int i = base + j;
        v[j] = (i < n) ? deg[i] : 0;
        run += v[j];
        s[j] = run;
    }
    int tsum = run;
    int x = tsum;
    #pragma unroll
    for (int m = 1; m < 64; m <<= 1) { int y = __shfl_up(x, m, 64); if (lane >= m) x += y; }
    int texcl = x - tsum;
    if (lane == 63) wtot[wid] = x;
    __syncthreads();
    if (t == 0) {
        int r = 0;
        #pragma unroll
        for (int w = 0; w < 4; ++w) { woff_s[w] = r; r += wtot[w]; }
    }
    __syncthreads();
    int ebase = boff[b] + woff_s[wid] + texcl;
    #pragma unroll
    for (int j = 0; j < 8; ++j) {
        int i = base + j;
        if (i < n) { int ex = ebase + s[j] - v[j]; rowptr[i] = ex; cursor[i] = ex; }
    }
}

__global__ void scatter_kernel(const int* __restrict__ row, const int* __restrict__ col,
                               int* __restrict__ cursor, int* __restrict__ cols_s, int e) {
    int i = blockIdx.x * blockDim.x + threadIdx.x;
    if (i < e) {
        int p = atomicAdd(&cursor[row[i]], 1);
        cols_s[p] = col[i];
    }
}

// ---------------- Chebyshev coefficients ----------------

__global__ void coef_kernel(const void* __restrict__ temp, const int* __restrict__ flag,
                            float* __restrict__ coe) {
    int i = threadIdx.x;
    bool isbf = flag[0] != 0;
    if (i <= K_ORDER) {
        float s = 0.0f;
        #pragma unroll
        for (int j = 0; j <= K_ORDER; ++j) {
            float t = isbf ? bf2f(((const unsigned short*)temp)[j]) : ((const float*)temp)[j];
            t = fmaxf(t, 0.0f);
            float theta = ((float)(K_ORDER - j) + 0.5f) * PI_F / (float)(K_ORDER + 1);
            s += cosf((float)i * theta) * t;
        }
        coe[i] = (2.0f / (float)(K_ORDER + 1)) * s;
    }
}

// ---------------- MFMA GEMM (unchanged, passed) ----------------

template<int BN, bool RELU, bool A_FLAGGED>
__global__ __launch_bounds__(256) void gemm_kernel(const void* __restrict__ A,
                                                   const void* __restrict__ B,
                                                   const void* __restrict__ bias,
                                                   const int* __restrict__ flag,
                                                   unsigned short* __restrict__ C,
                                                   int M, int Kdim, int ldc) {
    constexpr int BM = 128, BK = 32;
    constexpr int FN = BN / 32;
    constexpr int LDT = BK + 8;
    __shared__ unsigned short lds_a[BM * LDT] __attribute__((aligned(16)));
    __shared__ unsigned short lds_b[BN * LDT] __attribute__((aligned(16)));

    const bool isbf = flag[0] != 0;
    int tid = threadIdx.x;
    int lane = tid & 63, wid = tid >> 6;
    int row0 = blockIdx.x * BM;
    int col0 = blockIdx.y * BN;
    int wrow = (wid >> 1) * (BM / 2);
    int wcol = (wid & 1) * (BN / 2);

    f32x4 acc[4][FN] = {};

    for (int k0 = 0; k0 < Kdim; k0 += BK) {
        #pragma unroll
        for (int it = 0; it < (BM * BK / 8) / 256; ++it) {
            int idx = it * 256 + tid;
            int r = idx >> 2;
            int kc = (idx & 3) * 8;
            int gr = row0 + r; if (gr >= M) gr = M - 1;
            size_t base = (size_t)gr * Kdim + k0 + kc;
            if (!A_FLAGGED || isbf) {
                *(ushort8*)&lds_a[r * LDT + kc] = *(const ushort8*)((const unsigned short*)A + base);
            } else {
                const float* Af = (const float*)A;
                f32x4 lo = *(const f32x4*)(Af + base);
                f32x4 hi = *(const f32x4*)(Af + base + 4);
                bf16x8 v;
                #pragma unroll
                for (int j = 0; j < 4; ++j) { v[j] = (__bf16)lo[j]; v[j + 4] = (__bf16)hi[j]; }
                *(bf16x8*)&lds_a[r * LDT + kc] = v;
            }
        }
        #pragma unroll
        for (int it = 0; it < (BN * BK / 8) / 256; ++it) {
            int idx = it * 256 + tid;
            int r = idx >> 2;
            int kc = (idx & 3) * 8;
            size_t base = (size_t)(col0 + r) * Kdim + k0 + kc;
            if (isbf) {
                *(ushort8*)&lds_b[r * LDT + kc] = *(const ushort8*)((const unsigned short*)B + base);
            } else {
                const float* Bf = (const float*)B;
                f32x4 lo = *(const f32x4*)(Bf + base);
                f32x4 hi = *(const f32x4*)(Bf + base + 4);
                bf16x8 v;
                #pragma unroll
                for (int j = 0; j < 4; ++j) { v[j] = (__bf16)lo[j]; v[j + 4] = (__bf16)hi[j]; }
                *(bf16x8*)&lds_b[r * LDT + kc] = v;
            }
        }
        __syncthreads();

        int kq = (lane >> 4) * 8;
        bf16x8 af[4];
        bf16x8 bfr[FN];
        #pragma unroll
        for (int mi = 0; mi < 4; ++mi)
            af[mi] = *(bf16x8*)&lds_a[(wrow + mi * 16 + (lane & 15)) * LDT + kq];
        #pragma unroll
        for (int ni = 0; ni < FN; ++ni)
            bfr[ni] = *(bf16x8*)&lds_b[(wcol + ni * 16 + (lane & 15)) * LDT + kq];
        #pragma unroll
        for (int mi = 0; mi < 4; ++mi)
            #pragma unroll
            for (int ni = 0; ni < FN; ++ni)
                acc[mi][ni] = __builtin_amdgcn_mfma_f32_16x16x32_bf16(af[mi], bfr[ni],
                                                                      acc[mi][ni], 0, 0, 0);
        __syncthreads();
    }

    #pragma unroll
    for (int mi = 0; mi < 4; ++mi) {
        #pragma unroll
        for (int ni = 0; ni < FN; ++ni) {
            #pragma unroll
            for (int rg = 0; rg < 4; ++rg) {
                int grow = row0 + wrow + mi * 16 + (lane >> 4) * 4 + rg;
                int gcol = col0 + wcol + ni * 16 + (lane & 15);
                if (grow < M) {
                    float bb = isbf ? bf2f(((const unsigned short*)bias)[gcol])
                                    : ((const float*)bias)[gcol];
                    float vv = acc[mi][ni][rg] + bb;
                    if (RELU) vv = fmaxf(vv, 0.0f);
                    __bf16 h = (__bf16)vv;
                    C[(size_t)grow * ldc + gcol] = *(unsigned short*)&h;
                }
            }
        }
    }
}

// ---------------- Chebyshev propagation, vectorized ----------------
// One wave per row. lane = (sub=lane>>3 edge slot, fc=lane&7 feature chunk of 8).
// Each iter: wave covers 8 edges x 64 feats with 16B/lane loads.
// weight factored: P[r] = -dinv[r] * sum_edges dinv[c] * v[c]
// mode 0: tdst = P ; outacc = coe0/2 * vsrc[own] + coe1 * P
// mode 1: t2 = 2P - tdst[own]; tdst[own] = t2; outacc += coe[ci] * t2

__global__ __launch_bounds__(256) void prop_kernel(const unsigned short* __restrict__ vsrc,
                                                   unsigned short* __restrict__ tdst,
                                                   float* __restrict__ outacc,
                                                   const int* __restrict__ rowptr,
                                                   const int* __restrict__ cols,
                                                   const float* __restrict__ dinv,
                                                   const float* __restrict__ coe,
                                                   int mode, int ci, int n) {
    int lane = threadIdx.x & 63;
    int r = blockIdx.x * 4 + (threadIdx.x >> 6);
    if (r >= n) return;
    int fc = lane & 7;
    int sub = lane >> 3;
    int e0 = rowptr[r], e1 = rowptr[r + 1];
    float acc[8] = {};
    for (int e = e0; e < e1; e += 8) {
        int ee = e + sub;
        bool valid = ee < e1;
        int c = valid ? cols[ee] : 0;
        float w = valid ? dinv[c] : 0.0f;
        ushort8 vv = *(const ushort8*)&vsrc[(size_t)c * NOUT + fc * 8];
        #pragma unroll
        for (int j = 0; j < 8; ++j)
            acc[j] = fmaf(w, bf2f(vv[j]), acc[j]);
    }
    // reduce over sub (lanes differing in bits 3..5)
    #pragma unroll
    for (int m = 8; m < 64; m <<= 1)
        #pragma unroll
        for (int j = 0; j < 8; ++j)
            acc[j] += __shfl_xor(acc[j], m, 64);

    if (lane < 8) {   // lane w holds feats w*8 .. w*8+7 (fc==lane, sub==0)
        float dr = -dinv[r];
        size_t idx = (size_t)r * NOUT + lane * 8;
        float P[8];
        #pragma unroll
        for (int j = 0; j < 8; ++j) P[j] = dr * acc[j];
        if (mode == 0) {
            ushort8 v0 = *(const ushort8*)&vsrc[idx];
            ushort8 hout;
            #pragma unroll
            for (int j = 0; j < 8; ++j) {
                __bf16 h = (__bf16)P[j];
                hout[j] = *(unsigned short*)&h;
            }
            *(ushort8*)&tdst[idx] = hout;
            #pragma unroll
            for (int j = 0; j < 8; ++j)
                outacc[idx + j] = coe[0] * 0.5f * bf2f(v0[j]) + coe[1] * P[j];
        } else {
            ushort8 t0v = *(const ushort8*)&tdst[idx];
            ushort8 hout;
            float t2a[8];
            #pragma unroll
            for (int j = 0; j < 8; ++j) {
                float t2 = 2.0f * P[j] - bf2f(t0v[j]);
                t2a[j] = t2;
                __bf16 h = (__bf16)t2;
                hout[j] = *(unsigned short*)&h;
            }
            *(ushort8*)&tdst[idx] = hout;
            #pragma unroll
            for (int j = 0; j < 8; ++j)
                outacc[idx + j] += coe[ci] * t2a[j];
        }
    }
}

__global__ void convert_kernel(const float* __restrict__ in, const int* __restrict__ flag,
                               void* __restrict__ out, int n) {
    int i = blockIdx.x * blockDim.x + threadIdx.x;
    bool isbf = flag[0] != 0;
    if (i < n) {
        float v = in[i];
        if (isbf) {
            __bf16 h = (__bf16)v;
            ((unsigned short*)out)[i] = *(unsigned short*)&h;
        } else {
            ((float*)out)[i] = v;
        }
    }
}

// ---------------- launch ----------------

extern "C" void kernel_launch(void* const* d_in, const int* in_sizes, int n_in,
                              void* d_out, int out_size, void* d_ws, size_t ws_size,
                              hipStream_t stream) {
    const void* feature = d_in[0];
    const void* W1      = d_in[1];
    const void* b1      = d_in[2];
    const void* W2      = d_in[3];
    const void* b2      = d_in[4];
    const void* temp    = d_in[5];
    const int* edge_index = (const int*)d_in[6];

    const int N = in_sizes[0] / NFEAT;   // 100000
    const int E = in_sizes[6] / 2;       // 3200000
    const int* row = edge_index;
    const int* col = edge_index + E;
    const int nb = (N + SCAN_CHUNK - 1) / SCAN_CHUNK;   // 49

    char* base = (char*)d_ws;
    size_t off = 0;
    auto alloc = [&](size_t bytes) -> char* {
        char* p = base + off;
        off = (off + bytes + 255) & ~(size_t)255;
        return p;
    };
    int*   flag   = (int*)  alloc(4);
    float* coe    = (float*)alloc(64);
    int*   bsum   = (int*)  alloc(256);
    int*   boff   = (int*)  alloc(256);
    float* dinv   = (float*)alloc((size_t)N * 4);
    int*   deg    = (int*)  alloc((size_t)N * 4);
    int*   rowptr = (int*)  alloc((size_t)(N + 1) * 4);
    int*   cursor = (int*)  alloc((size_t)(N + 1) * 4);
    // overlay region R: xhid (N*NHID*2 = 51.2MB) lives gemm1->gemm2;
    // afterwards colss (E*4 = 12.8MB) | outacc (N*NOUT*4 = 25.6MB) live there.
    char*  R      = alloc((size_t)N * NHID * 2);
    unsigned short* xhid = (unsigned short*)R;
    int*   colss  = (int*)R;
    float* outacc = (float*)(R + (size_t)E * 4);
    unsigned short* t_a = (unsigned short*)alloc((size_t)N * NOUT * 2);
    unsigned short* t_b = (unsigned short*)alloc((size_t)N * NOUT * 2);

    // dtype flag + coefficients
    detect_kernel<<<1, 64, 0, stream>>>((const unsigned short*)temp, flag);
    coef_kernel<<<1, 64, 0, stream>>>(temp, flag, coe);

    // dense MLP (writes xhid, then t_a = Tx0 bf16)
    gemm_kernel<128, true, true><<<dim3((N + 127) / 128, NHID / 128), 256, 0, stream>>>(
        feature, W1, b1, flag, xhid, N, NFEAT, NHID);
    gemm_kernel<64, false, false><<<dim3((N + 127) / 128, 1), 256, 0, stream>>>(
        xhid, W2, b2, flag, t_a, N, NHID, NOUT);

    // graph preprocessing (xhid dead now; colss/outacc overlay it)
    hipMemsetAsync(deg, 0, (size_t)N * 4, stream);
    count_deg_kernel<<<(E + 255) / 256, 256, 0, stream>>>(row, deg, E);
    dinv_kernel<<<(N + 255) / 256, 256, 0, stream>>>(deg, dinv, N);
    partial_sum_kernel<<<nb, 256, 0, stream>>>(deg, bsum, N);
    scan_small_kernel<<<1, 64, 0, stream>>>(bsum, boff, rowptr, nb, N);
    scan_apply_kernel<<<nb, 256, 0, stream>>>(deg, boff, rowptr, cursor, N);
    scatter_kernel<<<(E + 255) / 256, 256, 0, stream>>>(row, col, cursor, colss, E);

    // Chebyshev propagation with 2 ping-pong bf16 buffers
    int pb = (N + 3) / 4;
    prop_kernel<<<pb, 256, 0, stream>>>(t_a, t_b, outacc, rowptr, colss, dinv, coe, 0, 0, N);
    unsigned short* src = t_b;
    unsigned short* dst = t_a;
    for (int i = 2; i <= K_ORDER; ++i) {
        prop_kernel<<<pb, 256, 0, stream>>>(src, dst, outacc, rowptr, colss, dinv, coe, 1, i, N);
        unsigned short* tmp = src; src = dst; dst = tmp;
    }

    convert_kernel<<<(N * NOUT + 255) / 256, 256, 0, stream>>>(outacc, flag, d_out, N * NOUT);
}